// Round 11
// baseline (2462.505 us; speedup 1.0000x reference)
//
#include <hip/hip_runtime.h>
#include <hip/hip_bf16.h>
#include <stdint.h>

typedef uint16_t u16;
typedef uint32_t u32;
typedef uint64_t u64;
typedef short bf16x8 __attribute__((ext_vector_type(8)));   // 8 bf16 in 4 VGPRs
typedef float f32x2 __attribute__((ext_vector_type(2)));
typedef float f32x4 __attribute__((ext_vector_type(4)));
typedef u32 u32x4 __attribute__((ext_vector_type(4)));

#define E_N 131072
#define T_N 1048576

__device__ __forceinline__ float bf2f(u32 u) { return __builtin_bit_cast(float, u << 16); }
__device__ __forceinline__ u16 f2bf(float f) {
  u32 u = __builtin_bit_cast(u32, f);
  return (u16)((u + 0x7fffu + ((u >> 16) & 1u)) >> 16);   // RNE
}
__device__ __forceinline__ float silu_f(float x) { return x / (1.0f + __expf(-x)); }
__device__ __forceinline__ f32x4 mfma16(bf16x8 a, bf16x8 b, f32x4 c) {
  return __builtin_amdgcn_mfma_f32_16x16x32_bf16(a, b, c, 0, 0, 0);
}
__device__ __forceinline__ void gld_lds16(const void* g, void* l) {
  __builtin_amdgcn_global_load_lds((const __attribute__((address_space(1))) u32*)g,
                                   (__attribute__((address_space(3))) u32*)l, 16, 0, 0);
}
#define WAIT_VM0() do { asm volatile("s_waitcnt vmcnt(0)" ::: "memory"); \
                        __builtin_amdgcn_sched_barrier(0); } while (0)

// Fragment-major weight layout (tiles x 4 ksteps): frag is 1KB, lane*16B.
__device__ __forceinline__ bf16x8 ldfrag(const char* base, u32 tile, u32 ks, u32 lane) {
  return *(const bf16x8*)(base + (((tile << 2) + ks) << 10) + lane * 16);
}

// ---------------------------------------------------------------------------
// k_init = fused weight-transpose (blocks 0..959) + ji-histogram (960..5055).
__global__ __launch_bounds__(256) void k_init(
    const float* __restrict__ Wji, const float* __restrict__ Wkj, const float* __restrict__ Wbil,
    const float* __restrict__ w11, const float* __restrict__ w12,
    const float* __restrict__ w21, const float* __restrict__ w22, const float* __restrict__ wout,
    u16* __restrict__ dst, const int* __restrict__ trip, int* __restrict__ cnt) {
  u32 bid = blockIdx.x;
  if (bid >= 960) {
    u32 t = (bid - 960) * 256 + threadIdx.x;
    atomicAdd(&cnt[trip[T_N + t]], 1);
    return;
  }
  u32 idx = bid * 256 + threadIdx.x;
  if (idx >= 245760) return;
  float v;
  if (idx < 163840) {   // fragment-major regions
    u32 j = idx & 7, lane = (idx >> 3) & 63, ks = (idx >> 9) & 3;
    u32 k = ((ks << 2) + (lane >> 4)) * 8 + j;
    u32 nl = lane & 15;
    if (idx < 32768) {
      u32 g = idx >> 11;
      u32 n = g * 16 + nl;
      v = (n < 128) ? Wji[k * 128 + n] : Wkj[k * 128 + (n - 128)];
    } else {
      u32 q = idx - 32768;
      u32 g = (q >> 11) & 7, b = q >> 14;
      v = Wbil[k * 1024 + b * 128 + g * 16 + nl];
    }
  } else {              // plain [n][k] for k_res staging
    u32 q = idx - 163840;
    u32 r = q >> 14, n = (q >> 7) & 127, h = q & 127;
    const float* src = (r == 0) ? w11 : (r == 1) ? w12 : (r == 2) ? w21 : (r == 3) ? w22 : wout;
    v = src[h * 128 + n];
  }
  dst[idx] = f2bf(v);
}

// ---------------------------------------------------------------------------
// Prefix-scan chain for the counting sort.
__global__ __launch_bounds__(256) void k_scanA(const int* __restrict__ cnt,
                                               int* __restrict__ offsA, int* __restrict__ blksum) {
  __shared__ int s[256];
  u32 b = blockIdx.x, tid = threadIdx.x;
  int v = cnt[b * 256 + tid];
  s[tid] = v; __syncthreads();
  for (int d = 1; d < 256; d <<= 1) {
    int t = (tid >= (u32)d) ? s[tid - d] : 0;
    __syncthreads(); s[tid] += t; __syncthreads();
  }
  offsA[b * 256 + tid] = s[tid] - v;
  if (tid == 255) blksum[b] = s[255];
}
__global__ __launch_bounds__(512) void k_scanB(const int* __restrict__ blksum, int* __restrict__ blkoff) {
  __shared__ int s[512];
  u32 tid = threadIdx.x;
  int v = blksum[tid];
  s[tid] = v; __syncthreads();
  for (int d = 1; d < 512; d <<= 1) {
    int t = (tid >= (u32)d) ? s[tid - d] : 0;
    __syncthreads(); s[tid] += t; __syncthreads();
  }
  blkoff[tid] = s[tid] - v;
}
__global__ __launch_bounds__(256) void k_scanC(const int* __restrict__ offsA,
                                               const int* __restrict__ blkoff, int* __restrict__ offs_work) {
  u32 i = blockIdx.x * 256 + threadIdx.x;
  offs_work[i] = offsA[i] + blkoff[blockIdx.x];
}

// ---------------------------------------------------------------------------
// k_mid = fused: blocks 0..1023 -> per-edge pre-GEMM;
//                blocks 1024..3071 -> sort-placement + sbf projection -> srec.
//  srec[p] (32B): {int kj, int ji, bf16 sp[8], pad} at ji-sorted position p.
__global__ __launch_bounds__(512) void k_mid(
    const float* __restrict__ m, const float* __restrict__ rbf, const float* __restrict__ Wrbf,
    const float* __restrict__ bkj, const float* __restrict__ bji,
    const char* __restrict__ W2F, float* __restrict__ aggr, u16* __restrict__ ek,
    const int* __restrict__ trip, const float* __restrict__ sbf, const float* __restrict__ Wsbf,
    int* __restrict__ offs_work, char* __restrict__ srec) {
  const u32 tid = threadIdx.x;
  if (blockIdx.x >= 1024) {
    // ---- placement + sbf projection (f32x2-vectorized row reads) ----
    u32 t = (blockIdx.x - 1024) * 512 + tid;
    int kj = trip[t], ji = trip[T_N + t];
    int p = atomicAdd(&offs_work[ji], 1);
    float o[8] = {0.f, 0.f, 0.f, 0.f, 0.f, 0.f, 0.f, 0.f};
    const float* sr = sbf + (size_t)t * 42;
#pragma unroll
    for (int q2 = 0; q2 < 21; ++q2) {
      f32x2 rv = *(const f32x2*)(sr + q2 * 2);
      const float* w0 = Wsbf + (q2 * 2) * 8;
#pragma unroll
      for (int c = 0; c < 8; ++c) o[c] += rv[0] * w0[c] + rv[1] * w0[8 + c];
    }
    u32x4 r0, r1;
    r0[0] = (u32)kj; r0[1] = (u32)ji;
    r0[2] = (u32)f2bf(o[0]) | ((u32)f2bf(o[1]) << 16);
    r0[3] = (u32)f2bf(o[2]) | ((u32)f2bf(o[3]) << 16);
    r1[0] = (u32)f2bf(o[4]) | ((u32)f2bf(o[5]) << 16);
    r1[1] = (u32)f2bf(o[6]) | ((u32)f2bf(o[7]) << 16);
    r1[2] = 0; r1[3] = 0;
    *(u32x4*)(srec + (size_t)p * 32) = r0;
    *(u32x4*)(srec + (size_t)p * 32 + 16) = r1;
    return;
  }
  // ---- per-edge pre-GEMM: [128 rows] x W2F(16 tiles) -> 256 cols ----
  extern __shared__ char lds[];
  char* ldsA = lds;                              // 32768
  float* ldsRbf = (float*)(lds + 32768);         // [128][6]
  float* ldsWr = (float*)(lds + 35840);          // [6][128]  -> total 38912
  const u32 lane = tid & 63;
  const u32 r0_ = blockIdx.x << 7;

#pragma unroll
  for (int it = 0; it < 8; ++it) {
    u32 q = tid + it * 512;
    u32 row = q >> 5, c4 = q & 31;
    f32x4 v = *(const f32x4*)(m + (size_t)(r0_ + row) * 128 + c4 * 4);
    u32 c = c4 >> 1, half = c4 & 1;
    u32 w0 = (u32)f2bf(v[0]) | ((u32)f2bf(v[1]) << 16);
    u32 w1 = (u32)f2bf(v[2]) | ((u32)f2bf(v[3]) << 16);
    u32 ofs = (row << 8) + ((c ^ (row & 7)) << 4) + half * 8;
    *(u64*)(ldsA + ofs) = (u64)w0 | ((u64)w1 << 32);
  }
  for (u32 i = tid; i < 768; i += 512) ldsRbf[i] = rbf[(size_t)r0_ * 6 + i];
  for (u32 i = tid; i < 768; i += 512) ldsWr[i] = Wrbf[i];
  __syncthreads();

  const u32 wid = tid >> 6, wm = wid >> 2, wn = wid & 3;
  const u32 rb = wm << 6, cb = wn << 6;
  f32x4 acc[4][4] = {};
  bf16x8 Bf[4][4];
#pragma unroll
  for (int ni = 0; ni < 4; ++ni)
#pragma unroll
    for (int ks = 0; ks < 4; ++ks) Bf[ni][ks] = ldfrag(W2F, wn * 4 + ni, ks, lane);
#pragma unroll
  for (int mi = 0; mi < 4; ++mi) {
    u32 row = rb + mi * 16 + (lane & 15);
    bf16x8 Af[4];
#pragma unroll
    for (int ks = 0; ks < 4; ++ks)
      Af[ks] = *(const bf16x8*)(ldsA + (row << 8) + ((((u32)(ks * 4) + (lane >> 4)) ^ (row & 7)) << 4));
#pragma unroll
    for (int ni = 0; ni < 4; ++ni)
#pragma unroll
      for (int ks = 0; ks < 4; ++ks) acc[mi][ni] = mfma16(Af[ks], Bf[ni][ks], acc[mi][ni]);
  }
#pragma unroll
  for (int mi = 0; mi < 4; ++mi) {
    u32 rloc = rb + mi * 16 + ((lane >> 4) << 2);
#pragma unroll
    for (int j = 0; j < 4; ++j) {
      u32 rl = rloc + j;
      size_t grow = r0_ + rl;
#pragma unroll
      for (int ni = 0; ni < 4; ++ni) {
        u32 col = cb + ni * 16 + (lane & 15);
        float v = acc[mi][ni][j];
        if (col < 128) {
          aggr[grow * 128 + col] = silu_f(v + bji[col]);
        } else {
          u32 c2 = col - 128;
          float rw = 0.f;
#pragma unroll
          for (int q = 0; q < 6; ++q) rw += ldsRbf[rl * 6 + q] * ldsWr[q * 128 + c2];
          ek[grow * 128 + c2] = f2bf(silu_f(v + bkj[c2]) * rw);
        }
      }
    }
  }
}

// ---------------------------------------------------------------------------
// S4 v6: 256 ji-sorted triplets / block, 512 threads (8 waves: 4 row-quarters
// x 2 col-halves).  Halves W L2 traffic per triplet; 76.8KB LDS -> 2 blk/CU
// = 16 waves/CU.  launch_bounds(512,4) caps 128 VGPR (body needs ~116; the
// r6/r9 spill cliff starts below that).
__global__ __launch_bounds__(512, 4) void k_bil(
    const char* __restrict__ ek, const char* __restrict__ srec,
    const char* __restrict__ WF, float* __restrict__ aggr) {
  extern __shared__ char lds[];
  char* Xl = lds;                         // [256 rows][256B] swizzled bf16 (65536)
  u16* msg16 = (u16*)lds;                 // [256][128] bf16 overlay (65536)
  float* spT = (float*)(lds + 65536);     // [8][256] f32 (8192)
  int* jil = (int*)(lds + 73728);         // 256
  int* kjl = (int*)(lds + 74752);         // 256
  int* rstart = (int*)(lds + 75776);      // 256
  int* scnt = (int*)(lds + 76800);        // 4   -> total 76816
  const u32 tid = threadIdx.x, lane = tid & 63, wid = tid >> 6;   // wid 0..7
  const u32 wm = wid >> 1, wn = wid & 1, rb = wm << 6, cb = wn << 6;
  const u32 t0 = blockIdx.x << 8;

  // phase A: coalesced srec read -> indices + spT
  if (tid < 256) {
    const char* rp = srec + (size_t)(t0 + tid) * 32;
    u32x4 a = *(const u32x4*)rp;
    u32 c0 = *(const u32*)(rp + 16);
    u32 c1 = *(const u32*)(rp + 20);
    kjl[tid] = (int)a[0];
    jil[tid] = (int)a[1];
    spT[0 * 256 + tid] = bf2f(a[2] & 0xffffu);
    spT[1 * 256 + tid] = bf2f(a[2] >> 16);
    spT[2 * 256 + tid] = bf2f(a[3] & 0xffffu);
    spT[3 * 256 + tid] = bf2f(a[3] >> 16);
    spT[4 * 256 + tid] = bf2f(c0 & 0xffffu);
    spT[5 * 256 + tid] = bf2f(c0 >> 16);
    spT[6 * 256 + tid] = bf2f(c1 & 0xffffu);
    spT[7 * 256 + tid] = bf2f(c1 >> 16);
  }
  __syncthreads();

  // phase B: X gather (async), 256 rows x 16 chunks
#pragma unroll
  for (int it = 0; it < 8; ++it) {
    u32 q = tid + it * 512, row = q >> 4, c = q & 15;
    gld_lds16(ek + (size_t)kjl[row] * 256 + ((c ^ (row & 7)) << 4), Xl + q * 16);
  }
  // run-detect overlaps the gather latency (4 waves cover 256 rows)
  int isS = 0;
  u32 pre = 0;
  if (tid < 256) {
    isS = (tid == 0) || (jil[tid] != jil[tid - 1]);
    u64 mask = __ballot(isS);
    pre = (u32)__popcll(mask & ((1ull << lane) - 1ull));
    if (lane == 0) scnt[wid] = (int)__popcll(mask);
  }
  WAIT_VM0();
  __syncthreads();
  if (tid < 256 && isS) {
    u32 off = 0;
    if (wid > 0) off += (u32)scnt[0];
    if (wid > 1) off += (u32)scnt[1];
    if (wid > 2) off += (u32)scnt[2];
    rstart[pre + off] = (int)tid;
  }

  // phase C: hoist X fragments to registers (wave: 64 rows x 64 cols)
  bf16x8 Afr[4][4];
#pragma unroll
  for (int mi = 0; mi < 4; ++mi) {
    u32 row = rb + mi * 16 + (lane & 15);
#pragma unroll
    for (int ks = 0; ks < 4; ++ks)
      Afr[mi][ks] = *(const bf16x8*)(Xl + (row << 8) + ((((u32)(ks * 4) + (lane >> 4)) ^ (row & 7)) << 4));
  }
  __syncthreads();   // all waves hoisted + rstart visible; X region reusable as msg

  // phase D: barrier-free b-loop, W fragments direct from global (L2-hot)
  f32x4 acc[4][4] = {};
  for (int b = 0; b < 8; ++b) {
    const char* wb = WF + (size_t)b * 32768;
    bf16x8 Bf[4][4];
#pragma unroll
    for (int ni = 0; ni < 4; ++ni)
#pragma unroll
      for (int ks = 0; ks < 4; ++ks) Bf[ni][ks] = ldfrag(wb, wn * 4 + ni, ks, lane);
#pragma unroll
    for (int mi = 0; mi < 4; ++mi) {
      f32x4 s4 = *(const f32x4*)(spT + b * 256 + rb + mi * 16 + ((lane >> 4) << 2));
#pragma unroll
      for (int ni = 0; ni < 4; ++ni) {
        f32x4 p = {0.f, 0.f, 0.f, 0.f};
#pragma unroll
        for (int ks = 0; ks < 4; ++ks) p = mfma16(Afr[mi][ks], Bf[ni][ks], p);
        acc[mi][ni] += s4 * p;
      }
    }
  }

  // phase E: spill acc -> bf16 msg (overlay X)
#pragma unroll
  for (int mi = 0; mi < 4; ++mi) {
    u32 rloc = rb + mi * 16 + ((lane >> 4) << 2);
#pragma unroll
    for (int j = 0; j < 4; ++j) {
      u16* drow = msg16 + (size_t)(rloc + j) * 128 + cb + (lane & 15);
#pragma unroll
      for (int ni = 0; ni < 4; ++ni) drow[ni * 16] = f2bf(acc[mi][ni][j]);
    }
  }
  __syncthreads();

  // phase F: one atomic per (run, col)
  const u32 nr = (u32)(scnt[0] + scnt[1] + scnt[2] + scnt[3]);
  for (u32 task = tid; task < nr * 128; task += 512) {
    u32 run = task >> 7, col = task & 127;
    int ra = rstart[run];
    int rz = (run + 1 < nr) ? rstart[run + 1] : 256;
    float s = 0.f;
    for (int r = ra; r < rz; ++r) s += bf2f(msg16[(size_t)r * 128 + col]);
    unsafeAtomicAdd(&aggr[(size_t)jil[ra] * 128 + col], s);
  }
}

// ---------------------------------------------------------------------------
// S5: fused residual chain (W staged to LDS, overlapped w/ epilogue).
__global__ __launch_bounds__(256, 2) void k_res(
    const float* __restrict__ aggr, const float* __restrict__ m,
    const char* __restrict__ rT,
    const float* __restrict__ rb1, const float* __restrict__ rb2,
    const float* __restrict__ rb3, const float* __restrict__ rb4,
    const float* __restrict__ bo, float* __restrict__ out) {
  extern __shared__ char lds[];
  char* ldsA = lds;
  char* ldsB = lds + 32768;
  const u32 tid = threadIdx.x, lane = tid & 63, wid = tid >> 6;
  const u32 r0 = blockIdx.x << 7;
  const u32 wm = wid >> 1, wn = wid & 1, rbw = wm << 6, cbw = wn << 6;
  const u32 lrow = (lane >> 4) << 2, lcol = lane & 15;

  auto stageB = [&](const char* WT) {
#pragma unroll
    for (int it = 0; it < 8; ++it) {
      u32 q = tid + it * 256, n = q >> 4, c = q & 15;
      gld_lds16(WT + n * 256 + ((c ^ (n & 7)) << 4), ldsB + q * 16);
    }
  };
  auto writeA = [&](u32 row, u32 col, float v) {
    *(u16*)(ldsA + (row << 8) + ((((col >> 3)) ^ (row & 7)) << 4) + (col & 7) * 2) = f2bf(v);
  };
  auto compute = [&](f32x4 (&acc)[4][4]) {
#pragma unroll
    for (int mi = 0; mi < 4; ++mi) {
      u32 row = rbw + mi * 16 + lcol;
      bf16x8 Af[4];
#pragma unroll
      for (int ks = 0; ks < 4; ++ks)
        Af[ks] = *(const bf16x8*)(ldsA + (row << 8) + ((((u32)(ks * 4) + (lane >> 4)) ^ (row & 7)) << 4));
#pragma unroll
      for (int ni = 0; ni < 4; ++ni) {
        u32 n = cbw + ni * 16 + lcol;
#pragma unroll
        for (int ks = 0; ks < 4; ++ks) {
          bf16x8 Bk = *(const bf16x8*)(ldsB + (n << 8) + ((((u32)(ks * 4) + (lane >> 4)) ^ (n & 7)) << 4));
          acc[mi][ni] = mfma16(Af[ks], Bk, acc[mi][ni]);
        }
      }
    }
  };
  auto zero = [&](f32x4 (&acc)[4][4]) {
#pragma unroll
    for (int a = 0; a < 4; ++a)
#pragma unroll
      for (int c = 0; c < 4; ++c) acc[a][c] = (f32x4){0.f, 0.f, 0.f, 0.f};
  };

  f32x4 xr[4][4];
#pragma unroll
  for (int mi = 0; mi < 4; ++mi)
#pragma unroll
    for (int j = 0; j < 4; ++j) {
      const float* src = aggr + (size_t)(r0 + rbw + mi * 16 + lrow + j) * 128 + cbw + lcol;
#pragma unroll
      for (int ni = 0; ni < 4; ++ni) xr[mi][ni][j] = src[ni * 16];
    }
  stageB(rT);
#pragma unroll
  for (int mi = 0; mi < 4; ++mi)
#pragma unroll
    for (int j = 0; j < 4; ++j) {
      u32 row = rbw + mi * 16 + lrow + j;
#pragma unroll
      for (int ni = 0; ni < 4; ++ni) writeA(row, cbw + ni * 16 + lcol, silu_f(xr[mi][ni][j]));
    }
  __syncthreads();

  f32x4 acc[4][4];
  zero(acc); compute(acc);
  __syncthreads();
#pragma unroll
  for (int mi = 0; mi < 4; ++mi)
#pragma unroll
    for (int j = 0; j < 4; ++j) {
      u32 row = rbw + mi * 16 + lrow + j;
#pragma unroll
      for (int ni = 0; ni < 4; ++ni) {
        u32 col = cbw + ni * 16 + lcol;
        writeA(row, col, silu_f(acc[mi][ni][j] + rb1[col]));
      }
    }
  stageB(rT + 32768);
  __syncthreads();

  zero(acc); compute(acc);
  __syncthreads();
#pragma unroll
  for (int mi = 0; mi < 4; ++mi)
#pragma unroll
    for (int j = 0; j < 4; ++j) {
      u32 row = rbw + mi * 16 + lrow + j;
#pragma unroll
      for (int ni = 0; ni < 4; ++ni) {
        u32 col = cbw + ni * 16 + lcol;
        xr[mi][ni][j] += acc[mi][ni][j] + rb2[col];
        writeA(row, col, silu_f(xr[mi][ni][j]));
      }
    }
  stageB(rT + 65536);
  __syncthreads();

  zero(acc); compute(acc);
  __syncthreads();
#pragma unroll
  for (int mi = 0; mi < 4; ++mi)
#pragma unroll
    for (int j = 0; j < 4; ++j) {
      u32 row = rbw + mi * 16 + lrow + j;
#pragma unroll
      for (int ni = 0; ni < 4; ++ni) {
        u32 col = cbw + ni * 16 + lcol;
        writeA(row, col, silu_f(acc[mi][ni][j] + rb3[col]));
      }
    }
  stageB(rT + 98304);
  __syncthreads();

  zero(acc); compute(acc);
  __syncthreads();
#pragma unroll
  for (int mi = 0; mi < 4; ++mi)
#pragma unroll
    for (int j = 0; j < 4; ++j) {
      u32 row = rbw + mi * 16 + lrow + j;
#pragma unroll
      for (int ni = 0; ni < 4; ++ni) {
        u32 col = cbw + ni * 16 + lcol;
        xr[mi][ni][j] += acc[mi][ni][j] + rb4[col];
        writeA(row, col, xr[mi][ni][j]);
      }
    }
  stageB(rT + 131072);
#pragma unroll
  for (int mi = 0; mi < 4; ++mi)
#pragma unroll
    for (int j = 0; j < 4; ++j) {
      const float* src = m + (size_t)(r0 + rbw + mi * 16 + lrow + j) * 128 + cbw + lcol;
#pragma unroll
      for (int ni = 0; ni < 4; ++ni) xr[mi][ni][j] = src[ni * 16];
    }
  __syncthreads();

  zero(acc); compute(acc);
#pragma unroll
  for (int mi = 0; mi < 4; ++mi)
#pragma unroll
    for (int j = 0; j < 4; ++j) {
      size_t grow = r0 + rbw + mi * 16 + lrow + j;
#pragma unroll
      for (int ni = 0; ni < 4; ++ni) {
        u32 col = cbw + ni * 16 + lcol;
        out[grow * 128 + col] = xr[mi][ni][j] + silu_f(acc[mi][ni][j] + bo[col]);
      }
    }
}

// ---------------------------------------------------------------------------
extern "C" void kernel_launch(void* const* d_in, const int* in_sizes, int n_in,
                              void* d_out, int out_size, void* d_ws, size_t ws_size,
                              hipStream_t stream) {
  const float* m = (const float*)d_in[0];
  const float* rbf = (const float*)d_in[1];
  const float* sbf = (const float*)d_in[2];
  const int* trip = (const int*)d_in[4];
  const float* Wrbf = (const float*)d_in[5];
  const float* Wsbf = (const float*)d_in[6];
  const float* bkj = (const float*)d_in[8];
  const float* bji = (const float*)d_in[10];
  const float* r1b1 = (const float*)d_in[13];
  const float* r1b2 = (const float*)d_in[15];
  const float* r2b1 = (const float*)d_in[17];
  const float* r2b2 = (const float*)d_in[19];
  const float* bout = (const float*)d_in[21];

  char* ws = (char*)d_ws;
  char* W2F = ws;                          // 65536 B (frag-major)
  char* WF = ws + 65536;                   // 262144 B (frag-major)
  char* rT = ws + 327680;                  // 163840 B (plain [n][k])
  u16* ek = (u16*)(ws + 524288);           // E*128 bf16 (33.5 MB)
  char* srec = ws + 34078720;              // T*32B sorted records (33.5 MB)
  float* aggr = (float*)(ws + 67633152);   // E*128 f32 (67 MB)
  int* cnt = (int*)(ws + 134742016);       // 131072 int
  int* offsA = (int*)(ws + 135266304);     // 131072 int
  int* blksum = (int*)(ws + 135790592);    // 512 int
  int* blkoff = (int*)(ws + 135792640);    // 512 int
  int* offs_work = (int*)(ws + 135794688); // 131072 int

  hipFuncSetAttribute((const void*)k_mid, hipFuncAttributeMaxDynamicSharedMemorySize, 38912);
  hipFuncSetAttribute((const void*)k_bil, hipFuncAttributeMaxDynamicSharedMemorySize, 76816);
  hipFuncSetAttribute((const void*)k_res, hipFuncAttributeMaxDynamicSharedMemorySize, 65536);

  hipMemsetAsync(cnt, 0, 131072 * sizeof(int), stream);
  k_init<<<5056, 256, 0, stream>>>(
      (const float*)d_in[9], (const float*)d_in[7], (const float*)d_in[11],
      (const float*)d_in[12], (const float*)d_in[14], (const float*)d_in[16],
      (const float*)d_in[18], (const float*)d_in[20], (u16*)ws, trip, cnt);
  k_scanA<<<512, 256, 0, stream>>>(cnt, offsA, blksum);
  k_scanB<<<1, 512, 0, stream>>>(blksum, blkoff);
  k_scanC<<<512, 256, 0, stream>>>(offsA, blkoff, offs_work);
  k_mid<<<3072, 512, 38912, stream>>>(m, rbf, Wrbf, bkj, bji, W2F, aggr, ek,
                                      trip, sbf, Wsbf, offs_work, srec);
  k_bil<<<4096, 512, 76816, stream>>>((const char*)ek, (const char*)srec, WF, aggr);
  k_res<<<1024, 256, 65536, stream>>>(aggr, m, rT, r1b1, r1b2, r2b1, r2b2, bout,
                                      (float*)d_out);
}

// Round 12
// 801.450 us; speedup vs baseline: 3.0726x; 3.0726x over previous
//
#include <hip/hip_runtime.h>
#include <hip/hip_bf16.h>
#include <stdint.h>

typedef uint16_t u16;
typedef uint32_t u32;
typedef uint64_t u64;
typedef short bf16x8 __attribute__((ext_vector_type(8)));   // 8 bf16 in 4 VGPRs
typedef float f32x2 __attribute__((ext_vector_type(2)));
typedef float f32x4 __attribute__((ext_vector_type(4)));
typedef u32 u32x4 __attribute__((ext_vector_type(4)));

#define E_N 131072
#define T_N 1048576

__device__ __forceinline__ float bf2f(u32 u) { return __builtin_bit_cast(float, u << 16); }
__device__ __forceinline__ u16 f2bf(float f) {
  u32 u = __builtin_bit_cast(u32, f);
  return (u16)((u + 0x7fffu + ((u >> 16) & 1u)) >> 16);   // RNE
}
__device__ __forceinline__ float silu_f(float x) { return x / (1.0f + __expf(-x)); }
__device__ __forceinline__ f32x4 mfma16(bf16x8 a, bf16x8 b, f32x4 c) {
  return __builtin_amdgcn_mfma_f32_16x16x32_bf16(a, b, c, 0, 0, 0);
}
__device__ __forceinline__ void gld_lds16(const void* g, void* l) {
  __builtin_amdgcn_global_load_lds((const __attribute__((address_space(1))) u32*)g,
                                   (__attribute__((address_space(3))) u32*)l, 16, 0, 0);
}
#define WAIT_VM0() do { asm volatile("s_waitcnt vmcnt(0)" ::: "memory"); \
                        __builtin_amdgcn_sched_barrier(0); } while (0)

// Fragment-major weight layout (tiles x 4 ksteps): frag is 1KB, lane*16B.
__device__ __forceinline__ bf16x8 ldfrag(const char* base, u32 tile, u32 ks, u32 lane) {
  return *(const bf16x8*)(base + (((tile << 2) + ks) << 10) + lane * 16);
}

// ---------------------------------------------------------------------------
// k_init = fused weight-transpose (blocks 0..959) + ji-histogram (960..5055).
__global__ __launch_bounds__(256) void k_init(
    const float* __restrict__ Wji, const float* __restrict__ Wkj, const float* __restrict__ Wbil,
    const float* __restrict__ w11, const float* __restrict__ w12,
    const float* __restrict__ w21, const float* __restrict__ w22, const float* __restrict__ wout,
    u16* __restrict__ dst, const int* __restrict__ trip, int* __restrict__ cnt) {
  u32 bid = blockIdx.x;
  if (bid >= 960) {
    u32 t = (bid - 960) * 256 + threadIdx.x;
    atomicAdd(&cnt[trip[T_N + t]], 1);
    return;
  }
  u32 idx = bid * 256 + threadIdx.x;
  if (idx >= 245760) return;
  float v;
  if (idx < 163840) {   // fragment-major regions
    u32 j = idx & 7, lane = (idx >> 3) & 63, ks = (idx >> 9) & 3;
    u32 k = ((ks << 2) + (lane >> 4)) * 8 + j;
    u32 nl = lane & 15;
    if (idx < 32768) {
      u32 g = idx >> 11;
      u32 n = g * 16 + nl;
      v = (n < 128) ? Wji[k * 128 + n] : Wkj[k * 128 + (n - 128)];
    } else {
      u32 q = idx - 32768;
      u32 g = (q >> 11) & 7, b = q >> 14;
      v = Wbil[k * 1024 + b * 128 + g * 16 + nl];
    }
  } else {              // plain [n][k] for k_res staging
    u32 q = idx - 163840;
    u32 r = q >> 14, n = (q >> 7) & 127, h = q & 127;
    const float* src = (r == 0) ? w11 : (r == 1) ? w12 : (r == 2) ? w21 : (r == 3) ? w22 : wout;
    v = src[h * 128 + n];
  }
  dst[idx] = f2bf(v);
}

// ---------------------------------------------------------------------------
// Prefix-scan chain for the counting sort.
__global__ __launch_bounds__(256) void k_scanA(const int* __restrict__ cnt,
                                               int* __restrict__ offsA, int* __restrict__ blksum) {
  __shared__ int s[256];
  u32 b = blockIdx.x, tid = threadIdx.x;
  int v = cnt[b * 256 + tid];
  s[tid] = v; __syncthreads();
  for (int d = 1; d < 256; d <<= 1) {
    int t = (tid >= (u32)d) ? s[tid - d] : 0;
    __syncthreads(); s[tid] += t; __syncthreads();
  }
  offsA[b * 256 + tid] = s[tid] - v;
  if (tid == 255) blksum[b] = s[255];
}
__global__ __launch_bounds__(512) void k_scanB(const int* __restrict__ blksum, int* __restrict__ blkoff) {
  __shared__ int s[512];
  u32 tid = threadIdx.x;
  int v = blksum[tid];
  s[tid] = v; __syncthreads();
  for (int d = 1; d < 512; d <<= 1) {
    int t = (tid >= (u32)d) ? s[tid - d] : 0;
    __syncthreads(); s[tid] += t; __syncthreads();
  }
  blkoff[tid] = s[tid] - v;
}
__global__ __launch_bounds__(256) void k_scanC(const int* __restrict__ offsA,
                                               const int* __restrict__ blkoff, int* __restrict__ offs_work) {
  u32 i = blockIdx.x * 256 + threadIdx.x;
  offs_work[i] = offsA[i] + blkoff[blockIdx.x];
}

// ---------------------------------------------------------------------------
// k_mid = fused: blocks 0..1023 -> per-edge pre-GEMM;
//                blocks 1024..3071 -> sort-placement + sbf projection -> srec.
//  srec[p] (32B): {int kj, int ji, bf16 sp[8], pad} at ji-sorted position p.
__global__ __launch_bounds__(512) void k_mid(
    const float* __restrict__ m, const float* __restrict__ rbf, const float* __restrict__ Wrbf,
    const float* __restrict__ bkj, const float* __restrict__ bji,
    const char* __restrict__ W2F, float* __restrict__ aggr, u16* __restrict__ ek,
    const int* __restrict__ trip, const float* __restrict__ sbf, const float* __restrict__ Wsbf,
    int* __restrict__ offs_work, char* __restrict__ srec) {
  const u32 tid = threadIdx.x;
  if (blockIdx.x >= 1024) {
    // ---- placement + sbf projection (f32x2-vectorized row reads) ----
    u32 t = (blockIdx.x - 1024) * 512 + tid;
    int kj = trip[t], ji = trip[T_N + t];
    int p = atomicAdd(&offs_work[ji], 1);
    float o[8] = {0.f, 0.f, 0.f, 0.f, 0.f, 0.f, 0.f, 0.f};
    const float* sr = sbf + (size_t)t * 42;
#pragma unroll
    for (int q2 = 0; q2 < 21; ++q2) {
      f32x2 rv = *(const f32x2*)(sr + q2 * 2);
      const float* w0 = Wsbf + (q2 * 2) * 8;
#pragma unroll
      for (int c = 0; c < 8; ++c) o[c] += rv[0] * w0[c] + rv[1] * w0[8 + c];
    }
    u32x4 r0, r1;
    r0[0] = (u32)kj; r0[1] = (u32)ji;
    r0[2] = (u32)f2bf(o[0]) | ((u32)f2bf(o[1]) << 16);
    r0[3] = (u32)f2bf(o[2]) | ((u32)f2bf(o[3]) << 16);
    r1[0] = (u32)f2bf(o[4]) | ((u32)f2bf(o[5]) << 16);
    r1[1] = (u32)f2bf(o[6]) | ((u32)f2bf(o[7]) << 16);
    r1[2] = 0; r1[3] = 0;
    *(u32x4*)(srec + (size_t)p * 32) = r0;
    *(u32x4*)(srec + (size_t)p * 32 + 16) = r1;
    return;
  }
  // ---- per-edge pre-GEMM: [128 rows] x W2F(16 tiles) -> 256 cols ----
  extern __shared__ char lds[];
  char* ldsA = lds;                              // 32768
  float* ldsRbf = (float*)(lds + 32768);         // [128][6]
  float* ldsWr = (float*)(lds + 35840);          // [6][128]  -> total 38912
  const u32 lane = tid & 63;
  const u32 r0_ = blockIdx.x << 7;

#pragma unroll
  for (int it = 0; it < 8; ++it) {
    u32 q = tid + it * 512;
    u32 row = q >> 5, c4 = q & 31;
    f32x4 v = *(const f32x4*)(m + (size_t)(r0_ + row) * 128 + c4 * 4);
    u32 c = c4 >> 1, half = c4 & 1;
    u32 w0 = (u32)f2bf(v[0]) | ((u32)f2bf(v[1]) << 16);
    u32 w1 = (u32)f2bf(v[2]) | ((u32)f2bf(v[3]) << 16);
    u32 ofs = (row << 8) + ((c ^ (row & 7)) << 4) + half * 8;
    *(u64*)(ldsA + ofs) = (u64)w0 | ((u64)w1 << 32);
  }
  for (u32 i = tid; i < 768; i += 512) ldsRbf[i] = rbf[(size_t)r0_ * 6 + i];
  for (u32 i = tid; i < 768; i += 512) ldsWr[i] = Wrbf[i];
  __syncthreads();

  const u32 wid = tid >> 6, wm = wid >> 2, wn = wid & 3;
  const u32 rb = wm << 6, cb = wn << 6;
  f32x4 acc[4][4] = {};
  bf16x8 Bf[4][4];
#pragma unroll
  for (int ni = 0; ni < 4; ++ni)
#pragma unroll
    for (int ks = 0; ks < 4; ++ks) Bf[ni][ks] = ldfrag(W2F, wn * 4 + ni, ks, lane);
#pragma unroll
  for (int mi = 0; mi < 4; ++mi) {
    u32 row = rb + mi * 16 + (lane & 15);
    bf16x8 Af[4];
#pragma unroll
    for (int ks = 0; ks < 4; ++ks)
      Af[ks] = *(const bf16x8*)(ldsA + (row << 8) + ((((u32)(ks * 4) + (lane >> 4)) ^ (row & 7)) << 4));
#pragma unroll
    for (int ni = 0; ni < 4; ++ni)
#pragma unroll
      for (int ks = 0; ks < 4; ++ks) acc[mi][ni] = mfma16(Af[ks], Bf[ni][ks], acc[mi][ni]);
  }
#pragma unroll
  for (int mi = 0; mi < 4; ++mi) {
    u32 rloc = rb + mi * 16 + ((lane >> 4) << 2);
#pragma unroll
    for (int j = 0; j < 4; ++j) {
      u32 rl = rloc + j;
      size_t grow = r0_ + rl;
#pragma unroll
      for (int ni = 0; ni < 4; ++ni) {
        u32 col = cb + ni * 16 + (lane & 15);
        float v = acc[mi][ni][j];
        if (col < 128) {
          aggr[grow * 128 + col] = silu_f(v + bji[col]);
        } else {
          u32 c2 = col - 128;
          float rw = 0.f;
#pragma unroll
          for (int q = 0; q < 6; ++q) rw += ldsRbf[rl * 6 + q] * ldsWr[q * 128 + c2];
          ek[grow * 128 + c2] = f2bf(silu_f(v + bkj[c2]) * rw);
        }
      }
    }
  }
}

// ---------------------------------------------------------------------------
// S4 v6b: 256 ji-sorted triplets / block, 512 threads (8 waves: 4 row-quarters
// x 2 col-halves).  launch_bounds(512,2) -> 256-VGPR budget: the ONLY cap this
// body has never spilled under (r6: 64 VGPR spill; r9: 84 spill; r11: 64 spill;
// r7/r10 at 256-budget: 116 VGPR, clean).  LDS 76.8KB -> 2 blk/CU; actual
// ~116 VGPR -> 4 waves/SIMD -> 16 waves/CU if the allocator stays <=128.
__global__ __launch_bounds__(512, 2) void k_bil(
    const char* __restrict__ ek, const char* __restrict__ srec,
    const char* __restrict__ WF, float* __restrict__ aggr) {
  extern __shared__ char lds[];
  char* Xl = lds;                         // [256 rows][256B] swizzled bf16 (65536)
  u16* msg16 = (u16*)lds;                 // [256][128] bf16 overlay (65536)
  float* spT = (float*)(lds + 65536);     // [8][256] f32 (8192)
  int* jil = (int*)(lds + 73728);         // 256
  int* kjl = (int*)(lds + 74752);         // 256
  int* rstart = (int*)(lds + 75776);      // 256
  int* scnt = (int*)(lds + 76800);        // 4   -> total 76816
  const u32 tid = threadIdx.x, lane = tid & 63, wid = tid >> 6;   // wid 0..7
  const u32 wm = wid >> 1, wn = wid & 1, rb = wm << 6, cb = wn << 6;
  const u32 t0 = blockIdx.x << 8;

  // phase A: coalesced srec read -> indices + spT
  if (tid < 256) {
    const char* rp = srec + (size_t)(t0 + tid) * 32;
    u32x4 a = *(const u32x4*)rp;
    u32 c0 = *(const u32*)(rp + 16);
    u32 c1 = *(const u32*)(rp + 20);
    kjl[tid] = (int)a[0];
    jil[tid] = (int)a[1];
    spT[0 * 256 + tid] = bf2f(a[2] & 0xffffu);
    spT[1 * 256 + tid] = bf2f(a[2] >> 16);
    spT[2 * 256 + tid] = bf2f(a[3] & 0xffffu);
    spT[3 * 256 + tid] = bf2f(a[3] >> 16);
    spT[4 * 256 + tid] = bf2f(c0 & 0xffffu);
    spT[5 * 256 + tid] = bf2f(c0 >> 16);
    spT[6 * 256 + tid] = bf2f(c1 & 0xffffu);
    spT[7 * 256 + tid] = bf2f(c1 >> 16);
  }
  __syncthreads();

  // phase B: X gather (async), 256 rows x 16 chunks
#pragma unroll
  for (int it = 0; it < 8; ++it) {
    u32 q = tid + it * 512, row = q >> 4, c = q & 15;
    gld_lds16(ek + (size_t)kjl[row] * 256 + ((c ^ (row & 7)) << 4), Xl + q * 16);
  }
  // run-detect overlaps the gather latency (4 waves cover 256 rows)
  int isS = 0;
  u32 pre = 0;
  if (tid < 256) {
    isS = (tid == 0) || (jil[tid] != jil[tid - 1]);
    u64 mask = __ballot(isS);
    pre = (u32)__popcll(mask & ((1ull << lane) - 1ull));
    if (lane == 0) scnt[wid] = (int)__popcll(mask);
  }
  WAIT_VM0();
  __syncthreads();
  if (tid < 256 && isS) {
    u32 off = 0;
    if (wid > 0) off += (u32)scnt[0];
    if (wid > 1) off += (u32)scnt[1];
    if (wid > 2) off += (u32)scnt[2];
    rstart[pre + off] = (int)tid;
  }

  // phase C: hoist X fragments to registers (wave: 64 rows x 64 cols)
  bf16x8 Afr[4][4];
#pragma unroll
  for (int mi = 0; mi < 4; ++mi) {
    u32 row = rb + mi * 16 + (lane & 15);
#pragma unroll
    for (int ks = 0; ks < 4; ++ks)
      Afr[mi][ks] = *(const bf16x8*)(Xl + (row << 8) + ((((u32)(ks * 4) + (lane >> 4)) ^ (row & 7)) << 4));
  }
  __syncthreads();   // all waves hoisted + rstart visible; X region reusable as msg

  // phase D: barrier-free b-loop, W fragments direct from global (L2-hot)
  f32x4 acc[4][4] = {};
  for (int b = 0; b < 8; ++b) {
    const char* wb = WF + (size_t)b * 32768;
    bf16x8 Bf[4][4];
#pragma unroll
    for (int ni = 0; ni < 4; ++ni)
#pragma unroll
      for (int ks = 0; ks < 4; ++ks) Bf[ni][ks] = ldfrag(wb, wn * 4 + ni, ks, lane);
#pragma unroll
    for (int mi = 0; mi < 4; ++mi) {
      f32x4 s4 = *(const f32x4*)(spT + b * 256 + rb + mi * 16 + ((lane >> 4) << 2));
#pragma unroll
      for (int ni = 0; ni < 4; ++ni) {
        f32x4 p = {0.f, 0.f, 0.f, 0.f};
#pragma unroll
        for (int ks = 0; ks < 4; ++ks) p = mfma16(Afr[mi][ks], Bf[ni][ks], p);
        acc[mi][ni] += s4 * p;
      }
    }
  }

  // phase E: spill acc -> bf16 msg (overlay X)
#pragma unroll
  for (int mi = 0; mi < 4; ++mi) {
    u32 rloc = rb + mi * 16 + ((lane >> 4) << 2);
#pragma unroll
    for (int j = 0; j < 4; ++j) {
      u16* drow = msg16 + (size_t)(rloc + j) * 128 + cb + (lane & 15);
#pragma unroll
      for (int ni = 0; ni < 4; ++ni) drow[ni * 16] = f2bf(acc[mi][ni][j]);
    }
  }
  __syncthreads();

  // phase F: one atomic per (run, col)
  const u32 nr = (u32)(scnt[0] + scnt[1] + scnt[2] + scnt[3]);
  for (u32 task = tid; task < nr * 128; task += 512) {
    u32 run = task >> 7, col = task & 127;
    int ra = rstart[run];
    int rz = (run + 1 < nr) ? rstart[run + 1] : 256;
    float s = 0.f;
    for (int r = ra; r < rz; ++r) s += bf2f(msg16[(size_t)r * 128 + col]);
    unsafeAtomicAdd(&aggr[(size_t)jil[ra] * 128 + col], s);
  }
}

// ---------------------------------------------------------------------------
// S5: fused residual chain (W staged to LDS, overlapped w/ epilogue).
__global__ __launch_bounds__(256, 2) void k_res(
    const float* __restrict__ aggr, const float* __restrict__ m,
    const char* __restrict__ rT,
    const float* __restrict__ rb1, const float* __restrict__ rb2,
    const float* __restrict__ rb3, const float* __restrict__ rb4,
    const float* __restrict__ bo, float* __restrict__ out) {
  extern __shared__ char lds[];
  char* ldsA = lds;
  char* ldsB = lds + 32768;
  const u32 tid = threadIdx.x, lane = tid & 63, wid = tid >> 6;
  const u32 r0 = blockIdx.x << 7;
  const u32 wm = wid >> 1, wn = wid & 1, rbw = wm << 6, cbw = wn << 6;
  const u32 lrow = (lane >> 4) << 2, lcol = lane & 15;

  auto stageB = [&](const char* WT) {
#pragma unroll
    for (int it = 0; it < 8; ++it) {
      u32 q = tid + it * 256, n = q >> 4, c = q & 15;
      gld_lds16(WT + n * 256 + ((c ^ (n & 7)) << 4), ldsB + q * 16);
    }
  };
  auto writeA = [&](u32 row, u32 col, float v) {
    *(u16*)(ldsA + (row << 8) + ((((col >> 3)) ^ (row & 7)) << 4) + (col & 7) * 2) = f2bf(v);
  };
  auto compute = [&](f32x4 (&acc)[4][4]) {
#pragma unroll
    for (int mi = 0; mi < 4; ++mi) {
      u32 row = rbw + mi * 16 + lcol;
      bf16x8 Af[4];
#pragma unroll
      for (int ks = 0; ks < 4; ++ks)
        Af[ks] = *(const bf16x8*)(ldsA + (row << 8) + ((((u32)(ks * 4) + (lane >> 4)) ^ (row & 7)) << 4));
#pragma unroll
      for (int ni = 0; ni < 4; ++ni) {
        u32 n = cbw + ni * 16 + lcol;
#pragma unroll
        for (int ks = 0; ks < 4; ++ks) {
          bf16x8 Bk = *(const bf16x8*)(ldsB + (n << 8) + ((((u32)(ks * 4) + (lane >> 4)) ^ (n & 7)) << 4));
          acc[mi][ni] = mfma16(Af[ks], Bk, acc[mi][ni]);
        }
      }
    }
  };
  auto zero = [&](f32x4 (&acc)[4][4]) {
#pragma unroll
    for (int a = 0; a < 4; ++a)
#pragma unroll
      for (int c = 0; c < 4; ++c) acc[a][c] = (f32x4){0.f, 0.f, 0.f, 0.f};
  };

  f32x4 xr[4][4];
#pragma unroll
  for (int mi = 0; mi < 4; ++mi)
#pragma unroll
    for (int j = 0; j < 4; ++j) {
      const float* src = aggr + (size_t)(r0 + rbw + mi * 16 + lrow + j) * 128 + cbw + lcol;
#pragma unroll
      for (int ni = 0; ni < 4; ++ni) xr[mi][ni][j] = src[ni * 16];
    }
  stageB(rT);
#pragma unroll
  for (int mi = 0; mi < 4; ++mi)
#pragma unroll
    for (int j = 0; j < 4; ++j) {
      u32 row = rbw + mi * 16 + lrow + j;
#pragma unroll
      for (int ni = 0; ni < 4; ++ni) writeA(row, cbw + ni * 16 + lcol, silu_f(xr[mi][ni][j]));
    }
  __syncthreads();

  f32x4 acc[4][4];
  zero(acc); compute(acc);
  __syncthreads();
#pragma unroll
  for (int mi = 0; mi < 4; ++mi)
#pragma unroll
    for (int j = 0; j < 4; ++j) {
      u32 row = rbw + mi * 16 + lrow + j;
#pragma unroll
      for (int ni = 0; ni < 4; ++ni) {
        u32 col = cbw + ni * 16 + lcol;
        writeA(row, col, silu_f(acc[mi][ni][j] + rb1[col]));
      }
    }
  stageB(rT + 32768);
  __syncthreads();

  zero(acc); compute(acc);
  __syncthreads();
#pragma unroll
  for (int mi = 0; mi < 4; ++mi)
#pragma unroll
    for (int j = 0; j < 4; ++j) {
      u32 row = rbw + mi * 16 + lrow + j;
#pragma unroll
      for (int ni = 0; ni < 4; ++ni) {
        u32 col = cbw + ni * 16 + lcol;
        xr[mi][ni][j] += acc[mi][ni][j] + rb2[col];
        writeA(row, col, silu_f(xr[mi][ni][j]));
      }
    }
  stageB(rT + 65536);
  __syncthreads();

  zero(acc); compute(acc);
  __syncthreads();
#pragma unroll
  for (int mi = 0; mi < 4; ++mi)
#pragma unroll
    for (int j = 0; j < 4; ++j) {
      u32 row = rbw + mi * 16 + lrow + j;
#pragma unroll
      for (int ni = 0; ni < 4; ++ni) {
        u32 col = cbw + ni * 16 + lcol;
        writeA(row, col, silu_f(acc[mi][ni][j] + rb3[col]));
      }
    }
  stageB(rT + 98304);
  __syncthreads();

  zero(acc); compute(acc);
  __syncthreads();
#pragma unroll
  for (int mi = 0; mi < 4; ++mi)
#pragma unroll
    for (int j = 0; j < 4; ++j) {
      u32 row = rbw + mi * 16 + lrow + j;
#pragma unroll
      for (int ni = 0; ni < 4; ++ni) {
        u32 col = cbw + ni * 16 + lcol;
        xr[mi][ni][j] += acc[mi][ni][j] + rb4[col];
        writeA(row, col, xr[mi][ni][j]);
      }
    }
  stageB(rT + 131072);
#pragma unroll
  for (int mi = 0; mi < 4; ++mi)
#pragma unroll
    for (int j = 0; j < 4; ++j) {
      const float* src = m + (size_t)(r0 + rbw + mi * 16 + lrow + j) * 128 + cbw + lcol;
#pragma unroll
      for (int ni = 0; ni < 4; ++ni) xr[mi][ni][j] = src[ni * 16];
    }
  __syncthreads();

  zero(acc); compute(acc);
#pragma unroll
  for (int mi = 0; mi < 4; ++mi)
#pragma unroll
    for (int j = 0; j < 4; ++j) {
      size_t grow = r0 + rbw + mi * 16 + lrow + j;
#pragma unroll
      for (int ni = 0; ni < 4; ++ni) {
        u32 col = cbw + ni * 16 + lcol;
        out[grow * 128 + col] = xr[mi][ni][j] + silu_f(acc[mi][ni][j] + bo[col]);
      }
    }
}

// ---------------------------------------------------------------------------
extern "C" void kernel_launch(void* const* d_in, const int* in_sizes, int n_in,
                              void* d_out, int out_size, void* d_ws, size_t ws_size,
                              hipStream_t stream) {
  const float* m = (const float*)d_in[0];
  const float* rbf = (const float*)d_in[1];
  const float* sbf = (const float*)d_in[2];
  const int* trip = (const int*)d_in[4];
  const float* Wrbf = (const float*)d_in[5];
  const float* Wsbf = (const float*)d_in[6];
  const float* bkj = (const float*)d_in[8];
  const float* bji = (const float*)d_in[10];
  const float* r1b1 = (const float*)d_in[13];
  const float* r1b2 = (const float*)d_in[15];
  const float* r2b1 = (const float*)d_in[17];
  const float* r2b2 = (const float*)d_in[19];
  const float* bout = (const float*)d_in[21];

  char* ws = (char*)d_ws;
  char* W2F = ws;                          // 65536 B (frag-major)
  char* WF = ws + 65536;                   // 262144 B (frag-major)
  char* rT = ws + 327680;                  // 163840 B (plain [n][k])
  u16* ek = (u16*)(ws + 524288);           // E*128 bf16 (33.5 MB)
  char* srec = ws + 34078720;              // T*32B sorted records (33.5 MB)
  float* aggr = (float*)(ws + 67633152);   // E*128 f32 (67 MB)
  int* cnt = (int*)(ws + 134742016);       // 131072 int
  int* offsA = (int*)(ws + 135266304);     // 131072 int
  int* blksum = (int*)(ws + 135790592);    // 512 int
  int* blkoff = (int*)(ws + 135792640);    // 512 int
  int* offs_work = (int*)(ws + 135794688); // 131072 int

  hipFuncSetAttribute((const void*)k_mid, hipFuncAttributeMaxDynamicSharedMemorySize, 38912);
  hipFuncSetAttribute((const void*)k_bil, hipFuncAttributeMaxDynamicSharedMemorySize, 76816);
  hipFuncSetAttribute((const void*)k_res, hipFuncAttributeMaxDynamicSharedMemorySize, 65536);

  hipMemsetAsync(cnt, 0, 131072 * sizeof(int), stream);
  k_init<<<5056, 256, 0, stream>>>(
      (const float*)d_in[9], (const float*)d_in[7], (const float*)d_in[11],
      (const float*)d_in[12], (const float*)d_in[14], (const float*)d_in[16],
      (const float*)d_in[18], (const float*)d_in[20], (u16*)ws, trip, cnt);
  k_scanA<<<512, 256, 0, stream>>>(cnt, offsA, blksum);
  k_scanB<<<1, 512, 0, stream>>>(blksum, blkoff);
  k_scanC<<<512, 256, 0, stream>>>(offsA, blkoff, offs_work);
  k_mid<<<3072, 512, 38912, stream>>>(m, rbf, Wrbf, bkj, bji, W2F, aggr, ek,
                                      trip, sbf, Wsbf, offs_work, srec);
  k_bil<<<4096, 512, 76816, stream>>>((const char*)ek, (const char*)srec, WF, aggr);
  k_res<<<1024, 256, 65536, stream>>>(aggr, m, rT, r1b1, r1b2, r2b1, r2b2, bout,
                                      (float*)d_out);
}

// Round 13
// 646.722 us; speedup vs baseline: 3.8077x; 1.2392x over previous
//
#include <hip/hip_runtime.h>
#include <hip/hip_bf16.h>
#include <stdint.h>

typedef uint16_t u16;
typedef uint32_t u32;
typedef uint64_t u64;
typedef short bf16x8 __attribute__((ext_vector_type(8)));   // 8 bf16 in 4 VGPRs
typedef float f32x2 __attribute__((ext_vector_type(2)));
typedef float f32x4 __attribute__((ext_vector_type(4)));
typedef u32 u32x4 __attribute__((ext_vector_type(4)));

#define E_N 131072
#define T_N 1048576

__device__ __forceinline__ float bf2f(u32 u) { return __builtin_bit_cast(float, u << 16); }
__device__ __forceinline__ u16 f2bf(float f) {
  u32 u = __builtin_bit_cast(u32, f);
  return (u16)((u + 0x7fffu + ((u >> 16) & 1u)) >> 16);   // RNE
}
__device__ __forceinline__ float silu_f(float x) { return x / (1.0f + __expf(-x)); }
__device__ __forceinline__ f32x4 mfma16(bf16x8 a, bf16x8 b, f32x4 c) {
  return __builtin_amdgcn_mfma_f32_16x16x32_bf16(a, b, c, 0, 0, 0);
}
__device__ __forceinline__ void gld_lds16(const void* g, void* l) {
  __builtin_amdgcn_global_load_lds((const __attribute__((address_space(1))) u32*)g,
                                   (__attribute__((address_space(3))) u32*)l, 16, 0, 0);
}
#define WAIT_VM0() do { asm volatile("s_waitcnt vmcnt(0)" ::: "memory"); \
                        __builtin_amdgcn_sched_barrier(0); } while (0)

// Fragment-major weight layout (tiles x 4 ksteps): frag is 1KB, lane*16B.
__device__ __forceinline__ bf16x8 ldfrag(const char* base, u32 tile, u32 ks, u32 lane) {
  return *(const bf16x8*)(base + (((tile << 2) + ks) << 10) + lane * 16);
}

// ---------------------------------------------------------------------------
// k_init = fused weight-transpose (blocks 0..959) + ji-histogram (960..5055).
__global__ __launch_bounds__(256) void k_init(
    const float* __restrict__ Wji, const float* __restrict__ Wkj, const float* __restrict__ Wbil,
    const float* __restrict__ w11, const float* __restrict__ w12,
    const float* __restrict__ w21, const float* __restrict__ w22, const float* __restrict__ wout,
    u16* __restrict__ dst, const int* __restrict__ trip, int* __restrict__ cnt) {
  u32 bid = blockIdx.x;
  if (bid >= 960) {
    u32 t = (bid - 960) * 256 + threadIdx.x;
    atomicAdd(&cnt[trip[T_N + t]], 1);
    return;
  }
  u32 idx = bid * 256 + threadIdx.x;
  if (idx >= 245760) return;
  float v;
  if (idx < 163840) {   // fragment-major regions
    u32 j = idx & 7, lane = (idx >> 3) & 63, ks = (idx >> 9) & 3;
    u32 k = ((ks << 2) + (lane >> 4)) * 8 + j;
    u32 nl = lane & 15;
    if (idx < 32768) {
      u32 g = idx >> 11;
      u32 n = g * 16 + nl;
      v = (n < 128) ? Wji[k * 128 + n] : Wkj[k * 128 + (n - 128)];
    } else {
      u32 q = idx - 32768;
      u32 g = (q >> 11) & 7, b = q >> 14;
      v = Wbil[k * 1024 + b * 128 + g * 16 + nl];
    }
  } else {              // plain [n][k] for k_res staging
    u32 q = idx - 163840;
    u32 r = q >> 14, n = (q >> 7) & 127, h = q & 127;
    const float* src = (r == 0) ? w11 : (r == 1) ? w12 : (r == 2) ? w21 : (r == 3) ? w22 : wout;
    v = src[h * 128 + n];
  }
  dst[idx] = f2bf(v);
}

// ---------------------------------------------------------------------------
// Prefix-scan chain (2 kernels; scanC self-computes its block offset).
__global__ __launch_bounds__(256) void k_scanA(const int* __restrict__ cnt,
                                               int* __restrict__ offsA, int* __restrict__ blksum) {
  __shared__ int s[256];
  u32 b = blockIdx.x, tid = threadIdx.x;
  int v = cnt[b * 256 + tid];
  s[tid] = v; __syncthreads();
  for (int d = 1; d < 256; d <<= 1) {
    int t = (tid >= (u32)d) ? s[tid - d] : 0;
    __syncthreads(); s[tid] += t; __syncthreads();
  }
  offsA[b * 256 + tid] = s[tid] - v;
  if (tid == 255) blksum[b] = s[255];
}
__global__ __launch_bounds__(256) void k_scanC(const int* __restrict__ offsA,
                                               const int* __restrict__ blksum,
                                               int* __restrict__ offs_work) {
  __shared__ int red[256];
  u32 bid = blockIdx.x, tid = threadIdx.x;
  int v = 0;
  if (tid < bid) v = blksum[tid];
  if (tid + 256 < bid) v += blksum[tid + 256];
  red[tid] = v; __syncthreads();
  for (int d = 128; d > 0; d >>= 1) {
    if (tid < (u32)d) red[tid] += red[tid + d];
    __syncthreads();
  }
  offs_work[bid * 256 + tid] = offsA[bid * 256 + tid] + red[0];
}

// ---------------------------------------------------------------------------
// k_mid = fused: blocks 0..1023 -> per-edge pre-GEMM;
//                blocks 1024..3071 -> sort-placement + sbf projection -> srec.
//  srec[p] (32B): {int kj, int ji, bf16 sp[8], pad} at ji-sorted position p.
__global__ __launch_bounds__(512) void k_mid(
    const float* __restrict__ m, const float* __restrict__ rbf, const float* __restrict__ Wrbf,
    const float* __restrict__ bkj, const float* __restrict__ bji,
    const char* __restrict__ W2F, float* __restrict__ aggr, u16* __restrict__ ek,
    const int* __restrict__ trip, const float* __restrict__ sbf, const float* __restrict__ Wsbf,
    int* __restrict__ offs_work, char* __restrict__ srec) {
  const u32 tid = threadIdx.x;
  if (blockIdx.x >= 1024) {
    // ---- placement + sbf projection (f32x2-vectorized row reads) ----
    u32 t = (blockIdx.x - 1024) * 512 + tid;
    int kj = trip[t], ji = trip[T_N + t];
    int p = atomicAdd(&offs_work[ji], 1);
    float o[8] = {0.f, 0.f, 0.f, 0.f, 0.f, 0.f, 0.f, 0.f};
    const float* sr = sbf + (size_t)t * 42;
#pragma unroll
    for (int q2 = 0; q2 < 21; ++q2) {
      f32x2 rv = *(const f32x2*)(sr + q2 * 2);
      const float* w0 = Wsbf + (q2 * 2) * 8;
#pragma unroll
      for (int c = 0; c < 8; ++c) o[c] += rv[0] * w0[c] + rv[1] * w0[8 + c];
    }
    u32x4 r0, r1;
    r0[0] = (u32)kj; r0[1] = (u32)ji;
    r0[2] = (u32)f2bf(o[0]) | ((u32)f2bf(o[1]) << 16);
    r0[3] = (u32)f2bf(o[2]) | ((u32)f2bf(o[3]) << 16);
    r1[0] = (u32)f2bf(o[4]) | ((u32)f2bf(o[5]) << 16);
    r1[1] = (u32)f2bf(o[6]) | ((u32)f2bf(o[7]) << 16);
    r1[2] = 0; r1[3] = 0;
    *(u32x4*)(srec + (size_t)p * 32) = r0;
    *(u32x4*)(srec + (size_t)p * 32 + 16) = r1;
    return;
  }
  // ---- per-edge pre-GEMM: [128 rows] x W2F(16 tiles) -> 256 cols ----
  extern __shared__ char lds[];
  char* ldsA = lds;                              // 32768
  float* ldsRbf = (float*)(lds + 32768);         // [128][6]
  float* ldsWr = (float*)(lds + 35840);          // [6][128]  -> total 38912
  const u32 lane = tid & 63;
  const u32 r0_ = blockIdx.x << 7;

#pragma unroll
  for (int it = 0; it < 8; ++it) {
    u32 q = tid + it * 512;
    u32 row = q >> 5, c4 = q & 31;
    f32x4 v = *(const f32x4*)(m + (size_t)(r0_ + row) * 128 + c4 * 4);
    u32 c = c4 >> 1, half = c4 & 1;
    u32 w0 = (u32)f2bf(v[0]) | ((u32)f2bf(v[1]) << 16);
    u32 w1 = (u32)f2bf(v[2]) | ((u32)f2bf(v[3]) << 16);
    u32 ofs = (row << 8) + ((c ^ (row & 7)) << 4) + half * 8;
    *(u64*)(ldsA + ofs) = (u64)w0 | ((u64)w1 << 32);
  }
  for (u32 i = tid; i < 768; i += 512) ldsRbf[i] = rbf[(size_t)r0_ * 6 + i];
  for (u32 i = tid; i < 768; i += 512) ldsWr[i] = Wrbf[i];
  __syncthreads();

  const u32 wid = tid >> 6, wm = wid >> 2, wn = wid & 3;
  const u32 rb = wm << 6, cb = wn << 6;
  f32x4 acc[4][4] = {};
  bf16x8 Bf[4][4];
#pragma unroll
  for (int ni = 0; ni < 4; ++ni)
#pragma unroll
    for (int ks = 0; ks < 4; ++ks) Bf[ni][ks] = ldfrag(W2F, wn * 4 + ni, ks, lane);
#pragma unroll
  for (int mi = 0; mi < 4; ++mi) {
    u32 row = rb + mi * 16 + (lane & 15);
    bf16x8 Af[4];
#pragma unroll
    for (int ks = 0; ks < 4; ++ks)
      Af[ks] = *(const bf16x8*)(ldsA + (row << 8) + ((((u32)(ks * 4) + (lane >> 4)) ^ (row & 7)) << 4));
#pragma unroll
    for (int ni = 0; ni < 4; ++ni)
#pragma unroll
      for (int ks = 0; ks < 4; ++ks) acc[mi][ni] = mfma16(Af[ks], Bf[ni][ks], acc[mi][ni]);
  }
#pragma unroll
  for (int mi = 0; mi < 4; ++mi) {
    u32 rloc = rb + mi * 16 + ((lane >> 4) << 2);
#pragma unroll
    for (int j = 0; j < 4; ++j) {
      u32 rl = rloc + j;
      size_t grow = r0_ + rl;
#pragma unroll
      for (int ni = 0; ni < 4; ++ni) {
        u32 col = cb + ni * 16 + (lane & 15);
        float v = acc[mi][ni][j];
        if (col < 128) {
          aggr[grow * 128 + col] = silu_f(v + bji[col]);
        } else {
          u32 c2 = col - 128;
          float rw = 0.f;
#pragma unroll
          for (int q = 0; q < 6; ++q) rw += ldsRbf[rl * 6 + q] * ldsWr[q * 128 + c2];
          ek[grow * 128 + c2] = f2bf(silu_f(v + bkj[c2]) * rw);
        }
      }
    }
  }
}

// ---------------------------------------------------------------------------
// S4 v5b (r10-exact, best-known 353us): 128 ji-sorted triplets / 256 threads.
// launch_bounds(256,2): the only no-spill config (r6/r9/r11: any tighter cap
// -> 64-84 VGPR -> ~1-4GB scratch traffic).
__global__ __launch_bounds__(256, 2) void k_bil(
    const char* __restrict__ ek, const char* __restrict__ srec,
    const char* __restrict__ WF, float* __restrict__ aggr) {
  extern __shared__ char lds[];
  char* Xl = lds;                         // [128 rows][256B] swizzled bf16 (32768)
  u16* msg16 = (u16*)lds;                 // [128][128] bf16 overlay (32768)
  float* spT = (float*)(lds + 32768);     // [8][128] f32 (4096)
  int* jil = (int*)(lds + 36864);         // 128
  int* kjl = (int*)(lds + 37376);         // 128
  int* rstart = (int*)(lds + 37888);      // 128
  int* scnt = (int*)(lds + 38400);        // 2   -> total 38408
  const u32 tid = threadIdx.x, lane = tid & 63, wid = tid >> 6;
  const u32 wm = wid >> 1, wn = wid & 1, rb = wm << 6, cb = wn << 6;
  const u32 t0 = blockIdx.x << 7;

  // phase A: coalesced srec read -> indices + spT
  if (tid < 128) {
    const char* rp = srec + (size_t)(t0 + tid) * 32;
    u32x4 a = *(const u32x4*)rp;
    u32 c0 = *(const u32*)(rp + 16);
    u32 c1 = *(const u32*)(rp + 20);
    kjl[tid] = (int)a[0];
    jil[tid] = (int)a[1];
    spT[0 * 128 + tid] = bf2f(a[2] & 0xffffu);
    spT[1 * 128 + tid] = bf2f(a[2] >> 16);
    spT[2 * 128 + tid] = bf2f(a[3] & 0xffffu);
    spT[3 * 128 + tid] = bf2f(a[3] >> 16);
    spT[4 * 128 + tid] = bf2f(c0 & 0xffffu);
    spT[5 * 128 + tid] = bf2f(c0 >> 16);
    spT[6 * 128 + tid] = bf2f(c1 & 0xffffu);
    spT[7 * 128 + tid] = bf2f(c1 >> 16);
  }
  __syncthreads();

  // phase B: X gather (async)
#pragma unroll
  for (int it = 0; it < 8; ++it) {
    u32 q = tid + it * 256, row = q >> 4, c = q & 15;
    gld_lds16(ek + (size_t)kjl[row] * 256 + ((c ^ (row & 7)) << 4), Xl + q * 16);
  }
  // run-detect overlaps the gather latency
  int isS = 0;
  u32 pre = 0;
  if (tid < 128) {
    isS = (tid == 0) || (jil[tid] != jil[tid - 1]);
    u64 mask = __ballot(isS);
    pre = (u32)__popcll(mask & ((1ull << lane) - 1ull));
    if (lane == 0) scnt[wid] = (int)__popcll(mask);
  }
  WAIT_VM0();
  __syncthreads();
  if (tid < 128 && isS) {
    u32 off = (wid == 1) ? (u32)scnt[0] : 0u;
    rstart[pre + off] = (int)tid;
  }

  // phase C: hoist X fragments to registers
  bf16x8 Afr[4][4];
#pragma unroll
  for (int mi = 0; mi < 4; ++mi) {
    u32 row = rb + mi * 16 + (lane & 15);
#pragma unroll
    for (int ks = 0; ks < 4; ++ks)
      Afr[mi][ks] = *(const bf16x8*)(Xl + (row << 8) + ((((u32)(ks * 4) + (lane >> 4)) ^ (row & 7)) << 4));
  }
  __syncthreads();   // all waves hoisted + rstart visible; X region reusable as msg

  // phase D: barrier-free b-loop, W fragments direct from global (L2-hot)
  f32x4 acc[4][4] = {};
  for (int b = 0; b < 8; ++b) {
    const char* wb = WF + (size_t)b * 32768;
    bf16x8 Bf[4][4];
#pragma unroll
    for (int ni = 0; ni < 4; ++ni)
#pragma unroll
      for (int ks = 0; ks < 4; ++ks) Bf[ni][ks] = ldfrag(wb, wn * 4 + ni, ks, lane);
#pragma unroll
    for (int mi = 0; mi < 4; ++mi) {
      f32x4 s4 = *(const f32x4*)(spT + b * 128 + rb + mi * 16 + ((lane >> 4) << 2));
#pragma unroll
      for (int ni = 0; ni < 4; ++ni) {
        f32x4 p = {0.f, 0.f, 0.f, 0.f};
#pragma unroll
        for (int ks = 0; ks < 4; ++ks) p = mfma16(Afr[mi][ks], Bf[ni][ks], p);
        acc[mi][ni] += s4 * p;
      }
    }
  }

  // phase E: spill acc -> bf16 msg (overlay X)
#pragma unroll
  for (int mi = 0; mi < 4; ++mi) {
    u32 rloc = rb + mi * 16 + ((lane >> 4) << 2);
#pragma unroll
    for (int j = 0; j < 4; ++j) {
      u16* drow = msg16 + (size_t)(rloc + j) * 128 + cb + (lane & 15);
#pragma unroll
      for (int ni = 0; ni < 4; ++ni) drow[ni * 16] = f2bf(acc[mi][ni][j]);
    }
  }
  __syncthreads();

  // phase F: one atomic per (run, col), contiguous cols per wave
  const u32 nr = (u32)(scnt[0] + scnt[1]);
  for (u32 task = tid; task < nr * 128; task += 256) {
    u32 run = task >> 7, col = task & 127;
    int ra = rstart[run];
    int rz = (run + 1 < nr) ? rstart[run + 1] : 128;
    float s = 0.f;
    for (int r = ra; r < rz; ++r) s += bf2f(msg16[(size_t)r * 128 + col]);
    unsafeAtomicAdd(&aggr[(size_t)jil[ra] * 128 + col], s);
  }
}

// ---------------------------------------------------------------------------
// S5 v2: fused residual chain, 64 rows/block (2048 blocks).  LDS 48KB ->
// 3 blocks/CU (12 waves, was 8): more cross-block overlap of the 11-barrier
// serial chain.  4 waves: wm (row half 0..1) x wn (col half 0..1).
__global__ __launch_bounds__(256, 2) void k_res(
    const float* __restrict__ aggr, const float* __restrict__ m,
    const char* __restrict__ rT,
    const float* __restrict__ rb1, const float* __restrict__ rb2,
    const float* __restrict__ rb3, const float* __restrict__ rb4,
    const float* __restrict__ bo, float* __restrict__ out) {
  extern __shared__ char lds[];
  char* ldsA = lds;                       // 64 rows x 256B = 16384
  char* ldsB = lds + 16384;               // 32768 -> total 49152
  const u32 tid = threadIdx.x, lane = tid & 63, wid = tid >> 6;
  const u32 r0 = blockIdx.x << 6;
  const u32 wm = wid >> 1, wn = wid & 1, rbw = wm << 5, cbw = wn << 6;
  const u32 lrow = (lane >> 4) << 2, lcol = lane & 15;

  auto stageB = [&](const char* WT) {
#pragma unroll
    for (int it = 0; it < 8; ++it) {
      u32 q = tid + it * 256, n = q >> 4, c = q & 15;
      gld_lds16(WT + n * 256 + ((c ^ (n & 7)) << 4), ldsB + q * 16);
    }
  };
  auto writeA = [&](u32 row, u32 col, float v) {
    *(u16*)(ldsA + (row << 8) + ((((col >> 3)) ^ (row & 7)) << 4) + (col & 7) * 2) = f2bf(v);
  };
  auto compute = [&](f32x4 (&acc)[2][4]) {
#pragma unroll
    for (int mi = 0; mi < 2; ++mi) {
      u32 row = rbw + mi * 16 + lcol;
      bf16x8 Af[4];
#pragma unroll
      for (int ks = 0; ks < 4; ++ks)
        Af[ks] = *(const bf16x8*)(ldsA + (row << 8) + ((((u32)(ks * 4) + (lane >> 4)) ^ (row & 7)) << 4));
#pragma unroll
      for (int ni = 0; ni < 4; ++ni) {
        u32 n = cbw + ni * 16 + lcol;
#pragma unroll
        for (int ks = 0; ks < 4; ++ks) {
          bf16x8 Bk = *(const bf16x8*)(ldsB + (n << 8) + ((((u32)(ks * 4) + (lane >> 4)) ^ (n & 7)) << 4));
          acc[mi][ni] = mfma16(Af[ks], Bk, acc[mi][ni]);
        }
      }
    }
  };
  auto zero = [&](f32x4 (&acc)[2][4]) {
#pragma unroll
    for (int a = 0; a < 2; ++a)
#pragma unroll
      for (int c = 0; c < 4; ++c) acc[a][c] = (f32x4){0.f, 0.f, 0.f, 0.f};
  };

  f32x4 xr[2][4];
#pragma unroll
  for (int mi = 0; mi < 2; ++mi)
#pragma unroll
    for (int j = 0; j < 4; ++j) {
      const float* src = aggr + (size_t)(r0 + rbw + mi * 16 + lrow + j) * 128 + cbw + lcol;
#pragma unroll
      for (int ni = 0; ni < 4; ++ni) xr[mi][ni][j] = src[ni * 16];
    }
  stageB(rT);
#pragma unroll
  for (int mi = 0; mi < 2; ++mi)
#pragma unroll
    for (int j = 0; j < 4; ++j) {
      u32 row = rbw + mi * 16 + lrow + j;
#pragma unroll
      for (int ni = 0; ni < 4; ++ni) writeA(row, cbw + ni * 16 + lcol, silu_f(xr[mi][ni][j]));
    }
  __syncthreads();

  f32x4 acc[2][4];
  // GEMM1: h1 = silu(. + b1)
  zero(acc); compute(acc);
  __syncthreads();
#pragma unroll
  for (int mi = 0; mi < 2; ++mi)
#pragma unroll
    for (int j = 0; j < 4; ++j) {
      u32 row = rbw + mi * 16 + lrow + j;
#pragma unroll
      for (int ni = 0; ni < 4; ++ni) {
        u32 col = cbw + ni * 16 + lcol;
        writeA(row, col, silu_f(acc[mi][ni][j] + rb1[col]));
      }
    }
  stageB(rT + 32768);
  __syncthreads();

  // GEMM2: x2 = x + . + b2 ; A3 = silu(x2)
  zero(acc); compute(acc);
  __syncthreads();
#pragma unroll
  for (int mi = 0; mi < 2; ++mi)
#pragma unroll
    for (int j = 0; j < 4; ++j) {
      u32 row = rbw + mi * 16 + lrow + j;
#pragma unroll
      for (int ni = 0; ni < 4; ++ni) {
        u32 col = cbw + ni * 16 + lcol;
        xr[mi][ni][j] += acc[mi][ni][j] + rb2[col];
        writeA(row, col, silu_f(xr[mi][ni][j]));
      }
    }
  stageB(rT + 65536);
  __syncthreads();

  // GEMM3: h2 = silu(. + b3)
  zero(acc); compute(acc);
  __syncthreads();
#pragma unroll
  for (int mi = 0; mi < 2; ++mi)
#pragma unroll
    for (int j = 0; j < 4; ++j) {
      u32 row = rbw + mi * 16 + lrow + j;
#pragma unroll
      for (int ni = 0; ni < 4; ++ni) {
        u32 col = cbw + ni * 16 + lcol;
        writeA(row, col, silu_f(acc[mi][ni][j] + rb3[col]));
      }
    }
  stageB(rT + 98304);
  __syncthreads();

  // GEMM4: x3 = x2 + . + b4 ; A5 = x3
  zero(acc); compute(acc);
  __syncthreads();
#pragma unroll
  for (int mi = 0; mi < 2; ++mi)
#pragma unroll
    for (int j = 0; j < 4; ++j) {
      u32 row = rbw + mi * 16 + lrow + j;
#pragma unroll
      for (int ni = 0; ni < 4; ++ni) {
        u32 col = cbw + ni * 16 + lcol;
        xr[mi][ni][j] += acc[mi][ni][j] + rb4[col];
        writeA(row, col, xr[mi][ni][j]);
      }
    }
  stageB(rT + 131072);
  // prefetch m into xr for final residual
#pragma unroll
  for (int mi = 0; mi < 2; ++mi)
#pragma unroll
    for (int j = 0; j < 4; ++j) {
      const float* src = m + (size_t)(r0 + rbw + mi * 16 + lrow + j) * 128 + cbw + lcol;
#pragma unroll
      for (int ni = 0; ni < 4; ++ni) xr[mi][ni][j] = src[ni * 16];
    }
  __syncthreads();

  // GEMM5: out = m + silu(. + bo)
  zero(acc); compute(acc);
#pragma unroll
  for (int mi = 0; mi < 2; ++mi)
#pragma unroll
    for (int j = 0; j < 4; ++j) {
      size_t grow = r0 + rbw + mi * 16 + lrow + j;
#pragma unroll
      for (int ni = 0; ni < 4; ++ni) {
        u32 col = cbw + ni * 16 + lcol;
        out[grow * 128 + col] = xr[mi][ni][j] + silu_f(acc[mi][ni][j] + bo[col]);
      }
    }
}

// ---------------------------------------------------------------------------
extern "C" void kernel_launch(void* const* d_in, const int* in_sizes, int n_in,
                              void* d_out, int out_size, void* d_ws, size_t ws_size,
                              hipStream_t stream) {
  const float* m = (const float*)d_in[0];
  const float* rbf = (const float*)d_in[1];
  const float* sbf = (const float*)d_in[2];
  const int* trip = (const int*)d_in[4];
  const float* Wrbf = (const float*)d_in[5];
  const float* Wsbf = (const float*)d_in[6];
  const float* bkj = (const float*)d_in[8];
  const float* bji = (const float*)d_in[10];
  const float* r1b1 = (const float*)d_in[13];
  const float* r1b2 = (const float*)d_in[15];
  const float* r2b1 = (const float*)d_in[17];
  const float* r2b2 = (const float*)d_in[19];
  const float* bout = (const float*)d_in[21];

  char* ws = (char*)d_ws;
  char* W2F = ws;                          // 65536 B (frag-major)
  char* WF = ws + 65536;                   // 262144 B (frag-major)
  char* rT = ws + 327680;                  // 163840 B (plain [n][k])
  u16* ek = (u16*)(ws + 524288);           // E*128 bf16 (33.5 MB)
  char* srec = ws + 34078720;              // T*32B sorted records (33.5 MB)
  float* aggr = (float*)(ws + 67633152);   // E*128 f32 (67 MB)
  int* cnt = (int*)(ws + 134742016);       // 131072 int
  int* offsA = (int*)(ws + 135266304);     // 131072 int
  int* blksum = (int*)(ws + 135790592);    // 512 int
  int* offs_work = (int*)(ws + 135794688); // 131072 int

  hipFuncSetAttribute((const void*)k_mid, hipFuncAttributeMaxDynamicSharedMemorySize, 38912);
  hipFuncSetAttribute((const void*)k_bil, hipFuncAttributeMaxDynamicSharedMemorySize, 38912);
  hipFuncSetAttribute((const void*)k_res, hipFuncAttributeMaxDynamicSharedMemorySize, 49152);

  hipMemsetAsync(cnt, 0, 131072 * sizeof(int), stream);
  k_init<<<5056, 256, 0, stream>>>(
      (const float*)d_in[9], (const float*)d_in[7], (const float*)d_in[11],
      (const float*)d_in[12], (const float*)d_in[14], (const float*)d_in[16],
      (const float*)d_in[18], (const float*)d_in[20], (u16*)ws, trip, cnt);
  k_scanA<<<512, 256, 0, stream>>>(cnt, offsA, blksum);
  k_scanC<<<512, 256, 0, stream>>>(offsA, blksum, offs_work);
  k_mid<<<3072, 512, 38912, stream>>>(m, rbf, Wrbf, bkj, bji, W2F, aggr, ek,
                                      trip, sbf, Wsbf, offs_work, srec);
  k_bil<<<8192, 256, 38912, stream>>>((const char*)ek, (const char*)srec, WF, aggr);
  k_res<<<2048, 256, 49152, stream>>>(aggr, m, rT, r1b1, r1b2, r2b1, r2b2, bout,
                                      (float*)d_out);
}